// Round 6
// baseline (544.142 us; speedup 1.0000x reference)
//
#include <hip/hip_runtime.h>
#include <math.h>

// ---------------------------------------------------------------------------
// CSDM pipeline on MI355X. fp32 in/out, fp32/bf16 intermediates in d_ws.
// B=4, C=32, H=W=256. MFMA head conv (A-frags direct from global),
// conflict-free padded hid transpose, fused dual-head gather tail,
// channel-last z0/y1/y2.
// ---------------------------------------------------------------------------

constexpr int B = 4, C = 32, H = 256, W = 256;
constexpr int HW = H * W;
constexpr int H1 = 128, W1 = 128, HW1 = H1 * W1;
constexpr int H2 = 64,  W2 = 64,  HW2 = H2 * W2;
constexpr int CH = 16;   // head hidden channels
constexpr int CO = 12;   // head output channels
constexpr int TILE = 16;
constexpr int HALO = 18;
constexpr int TAREA = HALO * HALO;   // 324
constexpr int WP = 258;              // padded q edge

typedef unsigned short ushort_t;
typedef __attribute__((ext_vector_type(8))) short bf16x8;
typedef __attribute__((ext_vector_type(4))) float f32x4;
typedef __attribute__((ext_vector_type(2))) float v2f;

static __device__ __forceinline__ float fast_rcp(float x) { return __builtin_amdgcn_rcpf(x); }
static __device__ __forceinline__ float silu_f(float x) { return x * fast_rcp(1.0f + __expf(-x)); }
static __device__ __forceinline__ v2f silu2(v2f x) {
    v2f r; r.x = silu_f(x.x); r.y = silu_f(x.y); return r;
}
static __device__ __forceinline__ float tanh_f(float x) {
    float xc = fminf(fmaxf(x, -15.0f), 15.0f);
    float e = __expf(2.0f * xc);
    return (e - 1.0f) * fast_rcp(e + 1.0f);
}
static __device__ __forceinline__ ushort_t f2b(float f) {   // fp32 -> bf16 RNE
    unsigned u = __float_as_uint(f);
    return (ushort_t)((u + 0x7fffu + ((u >> 16) & 1u)) >> 16);
}

// ---- pre: pool2 + qpad border + dall zero + w1 bf16 reorder ---------------
__global__ void pre_kernel(const float* __restrict__ x, float* __restrict__ s1,
                           ushort_t* __restrict__ qpad, float* __restrict__ dall,
                           const float* __restrict__ h1w1, const float* __restrict__ h2w1,
                           ushort_t* __restrict__ w1ra, ushort_t* __restrict__ w1rb) {
    int idx = blockIdx.x * blockDim.x + threadIdx.x;
    constexpr int NP = B * C * HW1;
    if (idx < NP) {
        int wo = idx % W1; int t = idx / W1;
        int ho = t % H1;   t /= H1;
        const float* src = x + ((size_t)t * H + (size_t)ho * 2) * W + (size_t)wo * 2;
        s1[idx] = (src[0] + src[1] + src[W] + src[W + 1]) * 0.25f;
        return;
    }
    int i = idx - NP;
    if (i < 4112) {                       // qpad border (4*1028)
        int b = i / 1028, r = i % 1028;
        int y, xx;
        if (r < 258)      { y = 0;           xx = r; }
        else if (r < 516) { y = 257;         xx = r - 258; }
        else if (r < 772) { y = r - 516 + 1; xx = 0; }
        else              { y = r - 772 + 1; xx = 257; }
        uint4 z4 = {0, 0, 0, 0};
        uint4* p = (uint4*)(qpad + (((size_t)b * WP + y) * WP + xx) * 32);
        p[0] = z4; p[1] = z4; p[2] = z4; p[3] = z4;
        return;
    }
    i -= 4112;
    if (i < 512) { dall[i] = 0.0f; return; }
    i -= 512;
    if (i < 4608) {                       // w1ra[o*288 + tap*32 + ci]
        int o = i / 288, k = i - o * 288;
        int j = k >> 5, ci = k & 31;
        w1ra[i] = f2b(h1w1[(o * C + ci) * 9 + j]);
        return;
    }
    i -= 4608;
    if (i < 4608) {
        int o = i / 288, k = i - o * 288;
        int j = k >> 5, ci = k & 31;
        w1rb[i] = f2b(h2w1[(o * C + ci) * 9 + j]);
    }
}

// ---- pool by 2 (s1 -> s2) -------------------------------------------------
__global__ void pool4_kernel(const float* __restrict__ s1, float* __restrict__ s2) {
    int idx = blockIdx.x * blockDim.x + threadIdx.x;
    if (idx >= B * C * HW2) return;
    int wo = idx % W2; int t = idx / W2;
    int ho = t % H2;   t /= H2;
    const float* src = s1 + ((size_t)t * H1 + (size_t)ho * 2) * W1 + (size_t)wo * 2;
    s2[idx] = (src[0] + src[1] + src[W1] + src[W1 + 1]) * 0.25f;
}

// ---- fused ds_block: dwconv3 + 1x1 + BN + SiLU (+ q-proj), packed f32 -----
// Writes z channel-last [b][p][c].
template<bool WITHQ>
__global__ __launch_bounds__(256, 4) void fused_ds_kernel(
        const float* __restrict__ in, const float* __restrict__ dw,
        const float* __restrict__ pw, const float* __restrict__ g,
        const float* __restrict__ bb, const float* __restrict__ m,
        const float* __restrict__ v, const float* __restrict__ qw,
        float* __restrict__ out, ushort_t* __restrict__ qout,
        int Hs, int Ws, int tilesX) {
    __shared__ unsigned tileu[16 * TAREA];     // 2-ch interleaved bf16, 20736 B
    __shared__ v2f dwp[16 * 9];
    __shared__ v2f pwp[C * 16];                // pwp[ci*16+o2] = {w[2o2][ci], w[2o2+1][ci]}
    __shared__ v2f qwp[WITHQ ? C * 16 : 1];
    __shared__ v2f scale2[16], shift2[16];
    int tid = threadIdx.x;
    int b = blockIdx.y;
    int HWs = Hs * Ws;
    int ox = (blockIdx.x % tilesX) * TILE;
    int oy = (blockIdx.x / tilesX) * TILE;

    for (int i = tid; i < 16 * 9; i += 256) {
        int c2 = i / 9, j = i - c2 * 9;
        dwp[i] = (v2f){dw[(2 * c2) * 9 + j], dw[(2 * c2 + 1) * 9 + j]};
    }
    for (int i = tid; i < C * 16; i += 256) {
        int ci = i >> 4, o2 = i & 15;
        pwp[i] = (v2f){pw[(2 * o2) * C + ci], pw[(2 * o2 + 1) * C + ci]};
        if (WITHQ) qwp[i] = (v2f){qw[(2 * o2) * C + ci], qw[(2 * o2 + 1) * C + ci]};
    }
    if (tid < 16) {
        float s0 = g[2 * tid] * rsqrtf(v[2 * tid] + 1e-5f);
        float s1v = g[2 * tid + 1] * rsqrtf(v[2 * tid + 1] + 1e-5f);
        scale2[tid] = (v2f){s0, s1v};
        shift2[tid] = (v2f){bb[2 * tid] - m[2 * tid] * s0, bb[2 * tid + 1] - m[2 * tid + 1] * s1v};
    }
    const float* src = in + (size_t)b * C * HWs;
    for (int i = tid; i < 16 * TAREA; i += 256) {
        int c2 = i / TAREA, r = i - c2 * TAREA;
        int yy = r / HALO, xx = r - yy * HALO;
        int gy = oy - 1 + yy, gx = ox - 1 + xx;
        float v0 = 0.0f, v1 = 0.0f;
        if (gy >= 0 && gy < Hs && gx >= 0 && gx < Ws) {
            const float* sp = src + (size_t)(2 * c2) * HWs + gy * Ws + gx;
            v0 = sp[0]; v1 = sp[HWs];
        }
        tileu[i] = (unsigned)f2b(v0) | ((unsigned)f2b(v1) << 16);
    }
    __syncthreads();

    int tx = tid & 15, ty = tid >> 4;
    int off[9];
#pragma unroll
    for (int jy = 0; jy < 3; ++jy)
#pragma unroll
        for (int jx = 0; jx < 3; ++jx)
            off[jy * 3 + jx] = (ty + jy) * HALO + tx + jx;

    v2f t2[16];
#pragma unroll
    for (int c2 = 0; c2 < 16; ++c2) {
        v2f s = {0.0f, 0.0f};
        const unsigned* tp = tileu + c2 * TAREA;
#pragma unroll
        for (int j = 0; j < 9; ++j) {
            unsigned u = tp[off[j]];
            v2f val = {__uint_as_float(u << 16), __uint_as_float(u & 0xffff0000u)};
            s += dwp[c2 * 9 + j] * val;
        }
        t2[c2] = s;
    }

    v2f acc2[16];
#pragma unroll
    for (int o2 = 0; o2 < 16; ++o2) acc2[o2] = (v2f){0.0f, 0.0f};
#pragma unroll
    for (int i2 = 0; i2 < 16; ++i2) {
        float ta = t2[i2].x, tb = t2[i2].y;
        const v2f* r0 = pwp + (2 * i2) * 16;
        const v2f* r1 = r0 + 16;
#pragma unroll
        for (int o2 = 0; o2 < 16; ++o2)
            acc2[o2] += r0[o2] * ta + r1[o2] * tb;
    }
#pragma unroll
    for (int o2 = 0; o2 < 16; ++o2)
        acc2[o2] = silu2(acc2[o2] * scale2[o2] + shift2[o2]);

    int px = ox + tx, py = oy + ty;
    int p = py * Ws + px;
    float4* dst = (float4*)(out + ((size_t)b * HWs + p) * C);
#pragma unroll
    for (int j = 0; j < 8; ++j)
        dst[j] = make_float4(acc2[2 * j].x, acc2[2 * j].y, acc2[2 * j + 1].x, acc2[2 * j + 1].y);

    if (WITHQ) {
        v2f q2[16];
#pragma unroll
        for (int o2 = 0; o2 < 16; ++o2) q2[o2] = (v2f){0.0f, 0.0f};
#pragma unroll
        for (int i2 = 0; i2 < 16; ++i2) {
            float ta = acc2[i2].x, tb = acc2[i2].y;
            const v2f* r0 = qwp + (2 * i2) * 16;
            const v2f* r1 = r0 + 16;
#pragma unroll
            for (int o2 = 0; o2 < 16; ++o2)
                q2[o2] += r0[o2] * ta + r1[o2] * tb;
        }
        unsigned up[16];
#pragma unroll
        for (int j = 0; j < 16; ++j)
            up[j] = (unsigned)f2b(q2[j].x) | ((unsigned)f2b(q2[j].y) << 16);
        uint4* qd = (uint4*)(qout + (((size_t)b * WP + py + 1) * WP + px + 1) * 32);
#pragma unroll
        for (int j = 0; j < 4; ++j)
            qd[j] = make_uint4(up[4 * j], up[4 * j + 1], up[4 * j + 2], up[4 * j + 3]);
    }
}

// ---- offsets/weights for one head ----------------------------------------
template<int HC, int WC>
static __device__ __forceinline__ void calc_off(const float* o12, int px, int py,
                                                int* zoff, float* wgt) {
    float mx = fmaxf(fmaxf(o12[8], o12[9]), fmaxf(o12[10], o12[11]));
    float e0 = __expf(o12[8] - mx), e1 = __expf(o12[9] - mx);
    float e2 = __expf(o12[10] - mx), e3 = __expf(o12[11] - mx);
    float inv = fast_rcp(e0 + e1 + e2 + e3);
    float wk4[4] = {e0 * inv, e1 * inv, e2 * inv, e3 * inv};
    float xc = (px + 0.5f) * ((float)WC / (float)W) - 0.5f;
    float yc = (py + 0.5f) * ((float)HC / (float)H) - 0.5f;
#pragma unroll
    for (int k = 0; k < 4; ++k) {
        float ix = fminf(fmaxf(xc + 2.0f * tanh_f(o12[2 * k]),     0.0f), (float)(WC - 1));
        float iy = fminf(fmaxf(yc + 2.0f * tanh_f(o12[2 * k + 1]), 0.0f), (float)(HC - 1));
        float x0f = floorf(ix), y0f = floorf(iy);
        int x0 = (int)x0f, y0 = (int)y0f;
        int x1 = min(x0 + 1, WC - 1), y1 = min(y0 + 1, HC - 1);
        float wx = ix - x0f, wy = iy - y0f;
        float wk = wk4[k];
        zoff[4 * k + 0] = (y0 * WC + x0) * C; wgt[4 * k + 0] = (1.0f - wx) * (1.0f - wy) * wk;
        zoff[4 * k + 1] = (y0 * WC + x1) * C; wgt[4 * k + 1] = wx * (1.0f - wy) * wk;
        zoff[4 * k + 2] = (y1 * WC + x0) * C; wgt[4 * k + 2] = (1.0f - wx) * wy * wk;
        zoff[4 * k + 3] = (y1 * WC + x1) * C; wgt[4 * k + 3] = wx * wy * wk;
    }
}

// ---- both heads: MFMA 3x3 conv + fused dual deform tail -------------------
// hidL: per-pixel 16 bf16, padded row stride 18 halfwords (9 dwords, odd
// -> 2-way max bank aliasing, free). Wave-local (writer pixels == reader
// tids for each wave), so no barrier around the hid round-trip.
__global__ __launch_bounds__(256, 4) void head_deform2_kernel(
        const ushort_t* __restrict__ qpad, const float* __restrict__ z1,
        const float* __restrict__ z2,
        const ushort_t* __restrict__ w1ra, const ushort_t* __restrict__ w1rb,
        const float* __restrict__ w2a, const float* __restrict__ b2a,
        const float* __restrict__ w2b, const float* __restrict__ b2b,
        float* __restrict__ y1, float* __restrict__ y2) {
    __shared__ __align__(16) ushort_t tile[TAREA * C];   // 20736 B
    __shared__ __align__(8)  unsigned hidw[256 * 9];     // 9216 B, stride 9 dwords
    int tid = threadIdx.x, b = blockIdx.y;
    int ox = (blockIdx.x & 15) * TILE, oy = (blockIdx.x >> 4) * TILE;
    int lane = tid & 63, wv = tid >> 6;
    int n15 = lane & 15, quad = lane >> 4;
    int tx = tid & 15, ty = tid >> 4;

    // stage q tile (rows contiguous in padded channel-last q)
    {
        const ushort_t* base = qpad + ((size_t)b * WP + oy) * WP * 32;
        uint4* tl = (uint4*)tile;
        for (int i = tid; i < 1296; i += 256) {      // 18 rows * 72 16B-chunks
            int yy = i / 72, r = i - yy * 72;
            tl[i] = *(const uint4*)(base + ((size_t)yy * WP + ox) * 32 + r * 8);
        }
    }
    __syncthreads();

    float hid1[CH], hid2[CH];
    // ---- head 1 conv (A-frags from global, L1-resident) ----
    {
        bf16x8 af[9];
#pragma unroll
        for (int j = 0; j < 9; ++j)
            af[j] = *(const bf16x8*)(w1ra + n15 * 288 + j * 32 + quad * 8);
#pragma unroll
        for (int g = 0; g < 4; ++g) {
            int yrow = wv * 4 + g;
            f32x4 acc = {0.0f, 0.0f, 0.0f, 0.0f};
#pragma unroll
            for (int jy = 0; jy < 3; ++jy)
#pragma unroll
                for (int jx = 0; jx < 3; ++jx) {
                    const bf16x8* bp = (const bf16x8*)(tile +
                        ((yrow + jy) * HALO + n15 + jx) * 32 + quad * 8);
                    acc = __builtin_amdgcn_mfma_f32_16x16x32_bf16(
                        af[jy * 3 + jx], *bp, acc, 0, 0, 0);
                }
            int pxl = yrow * 16 + n15;
            hidw[pxl * 9 + quad * 2]     = (unsigned)f2b(acc[0]) | ((unsigned)f2b(acc[1]) << 16);
            hidw[pxl * 9 + quad * 2 + 1] = (unsigned)f2b(acc[2]) | ((unsigned)f2b(acc[3]) << 16);
        }
#pragma unroll
        for (int j = 0; j < 8; ++j) {
            unsigned u = hidw[tid * 9 + j];
            hid1[2 * j]     = silu_f(__uint_as_float(u << 16));
            hid1[2 * j + 1] = silu_f(__uint_as_float(u & 0xffff0000u));
        }
    }
    // ---- head 2 conv (same hidL region; same-wave DS ordering is safe) ----
    {
        bf16x8 af[9];
#pragma unroll
        for (int j = 0; j < 9; ++j)
            af[j] = *(const bf16x8*)(w1rb + n15 * 288 + j * 32 + quad * 8);
#pragma unroll
        for (int g = 0; g < 4; ++g) {
            int yrow = wv * 4 + g;
            f32x4 acc = {0.0f, 0.0f, 0.0f, 0.0f};
#pragma unroll
            for (int jy = 0; jy < 3; ++jy)
#pragma unroll
                for (int jx = 0; jx < 3; ++jx) {
                    const bf16x8* bp = (const bf16x8*)(tile +
                        ((yrow + jy) * HALO + n15 + jx) * 32 + quad * 8);
                    acc = __builtin_amdgcn_mfma_f32_16x16x32_bf16(
                        af[jy * 3 + jx], *bp, acc, 0, 0, 0);
                }
            int pxl = yrow * 16 + n15;
            hidw[pxl * 9 + quad * 2]     = (unsigned)f2b(acc[0]) | ((unsigned)f2b(acc[1]) << 16);
            hidw[pxl * 9 + quad * 2 + 1] = (unsigned)f2b(acc[2]) | ((unsigned)f2b(acc[3]) << 16);
        }
#pragma unroll
        for (int j = 0; j < 8; ++j) {
            unsigned u = hidw[tid * 9 + j];
            hid2[2 * j]     = silu_f(__uint_as_float(u << 16));
            hid2[2 * j + 1] = silu_f(__uint_as_float(u & 0xffff0000u));
        }
    }

    // ---- fused dual tail ----
    float o12a[CO], o12b[CO];
#pragma unroll
    for (int j = 0; j < CO; ++j) {
        float a = b2a[j], c = b2b[j];
#pragma unroll
        for (int i = 0; i < CH; ++i) {
            a += w2a[j * CH + i] * hid1[i];
            c += w2b[j * CH + i] * hid2[i];
        }
        o12a[j] = a; o12b[j] = c;
    }
    int px = ox + tx, py = oy + ty;
    int off1[16], off2[16]; float wg1[16], wg2[16];
    calc_off<H1, W1>(o12a, px, py, off1, wg1);
    calc_off<H2, W2>(o12b, px, py, off2, wg2);

    const float* zb1 = z1 + (size_t)b * HW1 * C;
    const float* zb2 = z2 + (size_t)b * HW2 * C;
    int p = py * W + px;
    float* d1 = y1 + ((size_t)b * HW + p) * C;
    float* d2 = y2 + ((size_t)b * HW + p) * C;
#pragma unroll
    for (int c4 = 0; c4 < 8; ++c4) {
        f32x4 a1 = {0.0f, 0.0f, 0.0f, 0.0f};
        f32x4 a2 = {0.0f, 0.0f, 0.0f, 0.0f};
#pragma unroll
        for (int j = 0; j < 16; ++j) {
            a1 += wg1[j] * *(const f32x4*)(zb1 + off1[j] + c4 * 4);
            a2 += wg2[j] * *(const f32x4*)(zb2 + off2[j] + c4 * 4);
        }
        *(f32x4*)(d1 + c4 * 4) = a1;
        *(f32x4*)(d2 + c4 * 4) = a2;
    }
}

// ---- single-pass channel-last means via atomics ---------------------------
// grid: (b*3+src)*32 + chunk ; dall pre-zeroed by pre_kernel.
__global__ void mean3_kernel(const float* __restrict__ z0, const float* __restrict__ y1,
                             const float* __restrict__ y2, float* __restrict__ dall) {
    int id = blockIdx.x;
    int chunk = id & 31; int t = id >> 5;
    int src = t % 3, b = t / 3;
    const float* base = (src == 0 ? z0 : (src == 1 ? y1 : y2)) +
                        ((size_t)b * HW + chunk * 2048) * C;
    int tid = threadIdx.x, lane = tid & 63, wv = tid >> 6;
    f32x4 s = {0.0f, 0.0f, 0.0f, 0.0f};
    for (int i = tid; i < 16384; i += 256)          // 2048 px * 32 ch / 4
        s += *(const f32x4*)(base + i * 4);
    // lane holds channel group c4 = lane&7; fold lanes 8..63 into 0..7
#pragma unroll
    for (int o = 32; o >= 8; o >>= 1) {
        s[0] += __shfl_down(s[0], o, 64);
        s[1] += __shfl_down(s[1], o, 64);
        s[2] += __shfl_down(s[2], o, 64);
        s[3] += __shfl_down(s[3], o, 64);
    }
    __shared__ f32x4 ls[4][8];
    if (lane < 8) ls[wv][lane] = s;
    __syncthreads();
    if (tid < 8) {
        f32x4 v = ls[0][tid] + ls[1][tid] + ls[2][tid] + ls[3][tid];
        float* d = dall + b * 96 + src * 32 + tid * 4;
        atomicAdd(d + 0, v[0] * (1.0f / HW));
        atomicAdd(d + 1, v[1] * (1.0f / HW));
        atomicAdd(d + 2, v[2] * (1.0f / HW));
        atomicAdd(d + 3, v[3] * (1.0f / HW));
    }
}

// ---- gating MLP + softmax -> alpha[B*3] -----------------------------------
__global__ void gate_kernel(const float* __restrict__ dall,
                            const float* __restrict__ w1, const float* __restrict__ b1,
                            const float* __restrict__ w2, const float* __restrict__ b2,
                            float* __restrict__ alpha) {
    __shared__ float hid[B][32];
    int tid = threadIdx.x;
    int b = tid >> 5, j = tid & 31;
    float a = b1[j];
    for (int k = 0; k < 96; ++k) a += dall[b * 96 + k] * w1[k * 32 + j];
    hid[b][j] = silu_f(a);
    __syncthreads();
    if (j == 0) {
        float lg[3];
#pragma unroll
        for (int t = 0; t < 3; ++t) {
            float acc = b2[t];
            for (int jj = 0; jj < 32; ++jj) acc += hid[b][jj] * w2[jj * 3 + t];
            lg[t] = acc;
        }
        float mx = fmaxf(lg[0], fmaxf(lg[1], lg[2]));
        float e0 = __expf(lg[0] - mx), e1 = __expf(lg[1] - mx), e2 = __expf(lg[2] - mx);
        float inv = fast_rcp(e0 + e1 + e2);
        alpha[b * 3 + 0] = e0 * inv;
        alpha[b * 3 + 1] = e1 * inv;
        alpha[b * 3 + 2] = e2 * inv;
    }
}

// ---- fused mix + final 1x1 conv + residual (channel-last reads) -----------
__global__ __launch_bounds__(256, 4) void final_kernel(
        const float* __restrict__ x,
        const float* __restrict__ z0, const float* __restrict__ y1,
        const float* __restrict__ y2, const float* __restrict__ alpha,
        const float* __restrict__ fw, float* __restrict__ out) {
    __shared__ float ws[C * C];
    for (int i = threadIdx.x; i < C * C; i += blockDim.x) ws[i] = fw[i];
    __syncthreads();
    int idx = blockIdx.x * blockDim.x + threadIdx.x;
    if (idx >= B * HW) return;
    int b = idx / HW, p = idx - b * HW;
    float a0 = alpha[b * 3], a1 = alpha[b * 3 + 1], a2 = alpha[b * 3 + 2];
    size_t cl = ((size_t)b * HW + p) * C;
    float mix[C];
#pragma unroll
    for (int c4 = 0; c4 < 8; ++c4) {
        f32x4 za = *(const f32x4*)(z0 + cl + c4 * 4);
        f32x4 ya = *(const f32x4*)(y1 + cl + c4 * 4);
        f32x4 yb = *(const f32x4*)(y2 + cl + c4 * 4);
        f32x4 mm = a0 * za + a1 * ya + a2 * yb;
        mix[c4 * 4 + 0] = mm[0]; mix[c4 * 4 + 1] = mm[1];
        mix[c4 * 4 + 2] = mm[2]; mix[c4 * 4 + 3] = mm[3];
    }
    size_t pl = (size_t)b * C * HW + p;
#pragma unroll 4
    for (int o = 0; o < C; ++o) {
        float acc = 0.0f;
#pragma unroll
        for (int i = 0; i < C; ++i) acc += ws[o * C + i] * mix[i];
        size_t e = pl + (size_t)o * HW;
        out[e] = acc + x[e];
    }
}

// ---------------------------------------------------------------------------
extern "C" void kernel_launch(void* const* d_in, const int* in_sizes, int n_in,
                              void* d_out, int out_size, void* d_ws, size_t ws_size,
                              hipStream_t stream) {
    const float* x       = (const float*)d_in[0];
    const float* ds_dw[3] = {(const float*)d_in[1],  (const float*)d_in[7],  (const float*)d_in[13]};
    const float* ds_pw[3] = {(const float*)d_in[2],  (const float*)d_in[8],  (const float*)d_in[14]};
    const float* ds_g[3]  = {(const float*)d_in[3],  (const float*)d_in[9],  (const float*)d_in[15]};
    const float* ds_b[3]  = {(const float*)d_in[4],  (const float*)d_in[10], (const float*)d_in[16]};
    const float* ds_m[3]  = {(const float*)d_in[5],  (const float*)d_in[11], (const float*)d_in[17]};
    const float* ds_v[3]  = {(const float*)d_in[6],  (const float*)d_in[12], (const float*)d_in[18]};
    const float* qproj_w = (const float*)d_in[19];
    const float* h1_w1   = (const float*)d_in[20];
    const float* h1_w2   = (const float*)d_in[21];
    const float* h1_b2   = (const float*)d_in[22];
    const float* h2_w1   = (const float*)d_in[23];
    const float* h2_w2   = (const float*)d_in[24];
    const float* h2_b2   = (const float*)d_in[25];
    const float* r_w1    = (const float*)d_in[26];
    const float* r_b1    = (const float*)d_in[27];
    const float* r_w2    = (const float*)d_in[28];
    const float* r_b2    = (const float*)d_in[29];
    const float* final_w = (const float*)d_in[30];
    float* out = (float*)d_out;

    constexpr size_t N0 = (size_t)B * C * HW;
    constexpr size_t N1 = (size_t)B * C * HW1;
    constexpr size_t N2 = (size_t)B * C * HW2;
    constexpr size_t NQ = ((size_t)B * WP * WP * 32 + 1) / 2;   // qpad (u16) in floats

    float* w = (float*)d_ws;
    float* z0   = w; w += N0;      // channel-last
    float* y1   = w; w += N0;      // channel-last
    float* y2   = w; w += N0;      // channel-last
    float* z1cl = w; w += N1;
    float* z2cl = w; w += N2;
    float* s1   = w; w += N1;
    float* s2   = w; w += N2;
    ushort_t* qpad = (ushort_t*)w; w += NQ;
    ushort_t* w1ra = (ushort_t*)w; w += 2304;   // 4608 bf16
    ushort_t* w1rb = (ushort_t*)w; w += 2304;
    float* dall  = w; w += 512;
    float* alpha = w; w += 16;
    (void)ws_size; (void)in_sizes; (void)n_in; (void)out_size;

    const int T = 256;
    auto g = [](size_t n, int t) { return (int)((n + t - 1) / t); };

    pre_kernel<<<g(N1 + 4112 + 512 + 9216, T), T, 0, stream>>>(
        x, s1, qpad, dall, h1_w1, h2_w1, w1ra, w1rb);
    pool4_kernel<<<g(N2, T), T, 0, stream>>>(s1, s2);

    fused_ds_kernel<true><<<dim3((H / TILE) * (W / TILE), B), T, 0, stream>>>(
        x, ds_dw[0], ds_pw[0], ds_g[0], ds_b[0], ds_m[0], ds_v[0], qproj_w,
        z0, qpad, H, W, W / TILE);
    fused_ds_kernel<false><<<dim3((H1 / TILE) * (W1 / TILE), B), T, 0, stream>>>(
        s1, ds_dw[1], ds_pw[1], ds_g[1], ds_b[1], ds_m[1], ds_v[1], nullptr,
        z1cl, nullptr, H1, W1, W1 / TILE);
    fused_ds_kernel<false><<<dim3((H2 / TILE) * (W2 / TILE), B), T, 0, stream>>>(
        s2, ds_dw[2], ds_pw[2], ds_g[2], ds_b[2], ds_m[2], ds_v[2], nullptr,
        z2cl, nullptr, H2, W2, W2 / TILE);

    head_deform2_kernel<<<dim3((H / TILE) * (W / TILE), B), T, 0, stream>>>(
        qpad, z1cl, z2cl, w1ra, w1rb, h1_w2, h1_b2, h2_w2, h2_b2, y1, y2);

    mean3_kernel<<<384, T, 0, stream>>>(z0, y1, y2, dall);
    gate_kernel<<<1, 128, 0, stream>>>(dall, r_w1, r_b1, r_w2, r_b2, alpha);

    final_kernel<<<g((size_t)B * HW, T), T, 0, stream>>>(x, z0, y1, y2, alpha, final_w, out);
}

// Round 7
// 412.564 us; speedup vs baseline: 1.3189x; 1.3189x over previous
//
#include <hip/hip_runtime.h>
#include <math.h>

// ---------------------------------------------------------------------------
// CSDM pipeline on MI355X. fp32 in/out, fp32/bf16 intermediates in d_ws.
// B=4, C=32, H=W=256. MFMA head conv (A-frags direct from global),
// padded conflict-free hid transpose, fused dual-head gather tail.
// Layouts: z0/y1/y2 plane-major (dense stores); z1cl/z2cl/qpad channel-last
// (dense per-lane gather reads). Round 6 lesson: channel-last WRITES give
// 4x partial-line write amplification + L2 thrash -- never again.
// ---------------------------------------------------------------------------

constexpr int B = 4, C = 32, H = 256, W = 256;
constexpr int HW = H * W;
constexpr int H1 = 128, W1 = 128, HW1 = H1 * W1;
constexpr int H2 = 64,  W2 = 64,  HW2 = H2 * W2;
constexpr int CH = 16;   // head hidden channels
constexpr int CO = 12;   // head output channels
constexpr int TILE = 16;
constexpr int HALO = 18;
constexpr int TAREA = HALO * HALO;   // 324
constexpr int WP = 258;              // padded q edge

typedef unsigned short ushort_t;
typedef __attribute__((ext_vector_type(8))) short bf16x8;
typedef __attribute__((ext_vector_type(4))) float f32x4;
typedef __attribute__((ext_vector_type(2))) float v2f;

static __device__ __forceinline__ float fast_rcp(float x) { return __builtin_amdgcn_rcpf(x); }
static __device__ __forceinline__ float silu_f(float x) { return x * fast_rcp(1.0f + __expf(-x)); }
static __device__ __forceinline__ v2f silu2(v2f x) {
    v2f r; r.x = silu_f(x.x); r.y = silu_f(x.y); return r;
}
static __device__ __forceinline__ float tanh_f(float x) {
    float xc = fminf(fmaxf(x, -15.0f), 15.0f);
    float e = __expf(2.0f * xc);
    return (e - 1.0f) * fast_rcp(e + 1.0f);
}
static __device__ __forceinline__ ushort_t f2b(float f) {   // fp32 -> bf16 RNE
    unsigned u = __float_as_uint(f);
    return (ushort_t)((u + 0x7fffu + ((u >> 16) & 1u)) >> 16);
}

// ---- pre: pool2 + qpad border + w1 bf16 reorder ---------------------------
__global__ void pre_kernel(const float* __restrict__ x, float* __restrict__ s1,
                           ushort_t* __restrict__ qpad,
                           const float* __restrict__ h1w1, const float* __restrict__ h2w1,
                           ushort_t* __restrict__ w1ra, ushort_t* __restrict__ w1rb) {
    int idx = blockIdx.x * blockDim.x + threadIdx.x;
    constexpr int NP = B * C * HW1;
    if (idx < NP) {
        int wo = idx % W1; int t = idx / W1;
        int ho = t % H1;   t /= H1;
        const float* src = x + ((size_t)t * H + (size_t)ho * 2) * W + (size_t)wo * 2;
        s1[idx] = (src[0] + src[1] + src[W] + src[W + 1]) * 0.25f;
        return;
    }
    int i = idx - NP;
    if (i < 4112) {                       // qpad border (4*1028)
        int b = i / 1028, r = i % 1028;
        int y, xx;
        if (r < 258)      { y = 0;           xx = r; }
        else if (r < 516) { y = 257;         xx = r - 258; }
        else if (r < 772) { y = r - 516 + 1; xx = 0; }
        else              { y = r - 772 + 1; xx = 257; }
        uint4 z4 = {0, 0, 0, 0};
        uint4* p = (uint4*)(qpad + (((size_t)b * WP + y) * WP + xx) * 32);
        p[0] = z4; p[1] = z4; p[2] = z4; p[3] = z4;
        return;
    }
    i -= 4112;
    if (i < 4608) {                       // w1ra[o*288 + tap*32 + ci]
        int o = i / 288, k = i - o * 288;
        int j = k >> 5, ci = k & 31;
        w1ra[i] = f2b(h1w1[(o * C + ci) * 9 + j]);
        return;
    }
    i -= 4608;
    if (i < 4608) {
        int o = i / 288, k = i - o * 288;
        int j = k >> 5, ci = k & 31;
        w1rb[i] = f2b(h2w1[(o * C + ci) * 9 + j]);
    }
}

// ---- pool by 2 (s1 -> s2) -------------------------------------------------
__global__ void pool4_kernel(const float* __restrict__ s1, float* __restrict__ s2) {
    int idx = blockIdx.x * blockDim.x + threadIdx.x;
    if (idx >= B * C * HW2) return;
    int wo = idx % W2; int t = idx / W2;
    int ho = t % H2;   t /= H2;
    const float* src = s1 + ((size_t)t * H1 + (size_t)ho * 2) * W1 + (size_t)wo * 2;
    s2[idx] = (src[0] + src[1] + src[W1] + src[W1 + 1]) * 0.25f;
}

// ---- fused ds_block: dwconv3 + 1x1 + BN + SiLU (+ q-proj), packed f32 -----
// CHLAST: write z channel-last [b][p][c] (gather sources only); else plane.
template<bool CHLAST, bool WITHQ>
__global__ __launch_bounds__(256, 4) void fused_ds_kernel(
        const float* __restrict__ in, const float* __restrict__ dw,
        const float* __restrict__ pw, const float* __restrict__ g,
        const float* __restrict__ bb, const float* __restrict__ m,
        const float* __restrict__ v, const float* __restrict__ qw,
        float* __restrict__ out, ushort_t* __restrict__ qout,
        int Hs, int Ws, int tilesX) {
    __shared__ unsigned tileu[16 * TAREA];     // 2-ch interleaved bf16, 20736 B
    __shared__ v2f dwp[16 * 9];
    __shared__ v2f pwp[C * 16];                // pwp[ci*16+o2] = {w[2o2][ci], w[2o2+1][ci]}
    __shared__ v2f qwp[WITHQ ? C * 16 : 1];
    __shared__ v2f scale2[16], shift2[16];
    int tid = threadIdx.x;
    int b = blockIdx.y;
    int HWs = Hs * Ws;
    int ox = (blockIdx.x % tilesX) * TILE;
    int oy = (blockIdx.x / tilesX) * TILE;

    for (int i = tid; i < 16 * 9; i += 256) {
        int c2 = i / 9, j = i - c2 * 9;
        dwp[i] = (v2f){dw[(2 * c2) * 9 + j], dw[(2 * c2 + 1) * 9 + j]};
    }
    for (int i = tid; i < C * 16; i += 256) {
        int ci = i >> 4, o2 = i & 15;
        pwp[i] = (v2f){pw[(2 * o2) * C + ci], pw[(2 * o2 + 1) * C + ci]};
        if (WITHQ) qwp[i] = (v2f){qw[(2 * o2) * C + ci], qw[(2 * o2 + 1) * C + ci]};
    }
    if (tid < 16) {
        float s0 = g[2 * tid] * rsqrtf(v[2 * tid] + 1e-5f);
        float s1v = g[2 * tid + 1] * rsqrtf(v[2 * tid + 1] + 1e-5f);
        scale2[tid] = (v2f){s0, s1v};
        shift2[tid] = (v2f){bb[2 * tid] - m[2 * tid] * s0, bb[2 * tid + 1] - m[2 * tid + 1] * s1v};
    }
    const float* src = in + (size_t)b * C * HWs;
    for (int i = tid; i < 16 * TAREA; i += 256) {
        int c2 = i / TAREA, r = i - c2 * TAREA;
        int yy = r / HALO, xx = r - yy * HALO;
        int gy = oy - 1 + yy, gx = ox - 1 + xx;
        float v0 = 0.0f, v1 = 0.0f;
        if (gy >= 0 && gy < Hs && gx >= 0 && gx < Ws) {
            const float* sp = src + (size_t)(2 * c2) * HWs + gy * Ws + gx;
            v0 = sp[0]; v1 = sp[HWs];
        }
        tileu[i] = (unsigned)f2b(v0) | ((unsigned)f2b(v1) << 16);
    }
    __syncthreads();

    int tx = tid & 15, ty = tid >> 4;
    int off[9];
#pragma unroll
    for (int jy = 0; jy < 3; ++jy)
#pragma unroll
        for (int jx = 0; jx < 3; ++jx)
            off[jy * 3 + jx] = (ty + jy) * HALO + tx + jx;

    v2f t2[16];
#pragma unroll
    for (int c2 = 0; c2 < 16; ++c2) {
        v2f s = {0.0f, 0.0f};
        const unsigned* tp = tileu + c2 * TAREA;
#pragma unroll
        for (int j = 0; j < 9; ++j) {
            unsigned u = tp[off[j]];
            v2f val = {__uint_as_float(u << 16), __uint_as_float(u & 0xffff0000u)};
            s += dwp[c2 * 9 + j] * val;
        }
        t2[c2] = s;
    }

    v2f acc2[16];
#pragma unroll
    for (int o2 = 0; o2 < 16; ++o2) acc2[o2] = (v2f){0.0f, 0.0f};
#pragma unroll
    for (int i2 = 0; i2 < 16; ++i2) {
        float ta = t2[i2].x, tb = t2[i2].y;
        const v2f* r0 = pwp + (2 * i2) * 16;
        const v2f* r1 = r0 + 16;
#pragma unroll
        for (int o2 = 0; o2 < 16; ++o2)
            acc2[o2] += r0[o2] * ta + r1[o2] * tb;
    }
#pragma unroll
    for (int o2 = 0; o2 < 16; ++o2)
        acc2[o2] = silu2(acc2[o2] * scale2[o2] + shift2[o2]);

    int px = ox + tx, py = oy + ty;
    int p = py * Ws + px;
    if (CHLAST) {
        float4* dst = (float4*)(out + ((size_t)b * HWs + p) * C);
#pragma unroll
        for (int j = 0; j < 8; ++j)
            dst[j] = make_float4(acc2[2 * j].x, acc2[2 * j].y, acc2[2 * j + 1].x, acc2[2 * j + 1].y);
    } else {
        float* dst = out + (size_t)b * C * HWs + p;
#pragma unroll
        for (int o2 = 0; o2 < 16; ++o2) {
            dst[(size_t)(2 * o2) * HWs] = acc2[o2].x;
            dst[(size_t)(2 * o2 + 1) * HWs] = acc2[o2].y;
        }
    }
    if (WITHQ) {
        v2f q2[16];
#pragma unroll
        for (int o2 = 0; o2 < 16; ++o2) q2[o2] = (v2f){0.0f, 0.0f};
#pragma unroll
        for (int i2 = 0; i2 < 16; ++i2) {
            float ta = acc2[i2].x, tb = acc2[i2].y;
            const v2f* r0 = qwp + (2 * i2) * 16;
            const v2f* r1 = r0 + 16;
#pragma unroll
            for (int o2 = 0; o2 < 16; ++o2)
                q2[o2] += r0[o2] * ta + r1[o2] * tb;
        }
        unsigned up[16];
#pragma unroll
        for (int j = 0; j < 16; ++j)
            up[j] = (unsigned)f2b(q2[j].x) | ((unsigned)f2b(q2[j].y) << 16);
        uint4* qd = (uint4*)(qout + (((size_t)b * WP + py + 1) * WP + px + 1) * 32);
#pragma unroll
        for (int j = 0; j < 4; ++j)
            qd[j] = make_uint4(up[4 * j], up[4 * j + 1], up[4 * j + 2], up[4 * j + 3]);
    }
}

// ---- offsets/weights for one head ----------------------------------------
template<int HC, int WC>
static __device__ __forceinline__ void calc_off(const float* o12, int px, int py,
                                                int* zoff, float* wgt) {
    float mx = fmaxf(fmaxf(o12[8], o12[9]), fmaxf(o12[10], o12[11]));
    float e0 = __expf(o12[8] - mx), e1 = __expf(o12[9] - mx);
    float e2 = __expf(o12[10] - mx), e3 = __expf(o12[11] - mx);
    float inv = fast_rcp(e0 + e1 + e2 + e3);
    float wk4[4] = {e0 * inv, e1 * inv, e2 * inv, e3 * inv};
    float xc = (px + 0.5f) * ((float)WC / (float)W) - 0.5f;
    float yc = (py + 0.5f) * ((float)HC / (float)H) - 0.5f;
#pragma unroll
    for (int k = 0; k < 4; ++k) {
        float ix = fminf(fmaxf(xc + 2.0f * tanh_f(o12[2 * k]),     0.0f), (float)(WC - 1));
        float iy = fminf(fmaxf(yc + 2.0f * tanh_f(o12[2 * k + 1]), 0.0f), (float)(HC - 1));
        float x0f = floorf(ix), y0f = floorf(iy);
        int x0 = (int)x0f, y0 = (int)y0f;
        int x1 = min(x0 + 1, WC - 1), y1 = min(y0 + 1, HC - 1);
        float wx = ix - x0f, wy = iy - y0f;
        float wk = wk4[k];
        zoff[4 * k + 0] = (y0 * WC + x0) * C; wgt[4 * k + 0] = (1.0f - wx) * (1.0f - wy) * wk;
        zoff[4 * k + 1] = (y0 * WC + x1) * C; wgt[4 * k + 1] = wx * (1.0f - wy) * wk;
        zoff[4 * k + 2] = (y1 * WC + x0) * C; wgt[4 * k + 2] = (1.0f - wx) * wy * wk;
        zoff[4 * k + 3] = (y1 * WC + x1) * C; wgt[4 * k + 3] = wx * wy * wk;
    }
}

// ---- both heads: MFMA 3x3 conv + fused dual deform tail, plane-major y ----
// hidw: per-pixel 16 bf16 at row stride 9 dwords (odd -> <=2-way aliasing,
// free). Wave-local (writer pixels == reader tids per wave): no barrier.
__global__ __launch_bounds__(256, 4) void head_deform2_kernel(
        const ushort_t* __restrict__ qpad, const float* __restrict__ z1,
        const float* __restrict__ z2,
        const ushort_t* __restrict__ w1ra, const ushort_t* __restrict__ w1rb,
        const float* __restrict__ w2a, const float* __restrict__ b2a,
        const float* __restrict__ w2b, const float* __restrict__ b2b,
        float* __restrict__ y1, float* __restrict__ y2) {
    __shared__ __align__(16) ushort_t tile[TAREA * C];   // 20736 B
    __shared__ __align__(8)  unsigned hidw[256 * 9];     // 9216 B, stride 9 dwords
    int tid = threadIdx.x, b = blockIdx.y;
    int ox = (blockIdx.x & 15) * TILE, oy = (blockIdx.x >> 4) * TILE;
    int lane = tid & 63, wv = tid >> 6;
    int n15 = lane & 15, quad = lane >> 4;
    int tx = tid & 15, ty = tid >> 4;

    // stage q tile (rows contiguous in padded channel-last q)
    {
        const ushort_t* base = qpad + ((size_t)b * WP + oy) * WP * 32;
        uint4* tl = (uint4*)tile;
        for (int i = tid; i < 1296; i += 256) {      // 18 rows * 72 16B-chunks
            int yy = i / 72, r = i - yy * 72;
            tl[i] = *(const uint4*)(base + ((size_t)yy * WP + ox) * 32 + r * 8);
        }
    }
    __syncthreads();

    float hid1[CH], hid2[CH];
    // ---- head 1 conv (A-frags from global, L2-resident) ----
    {
        bf16x8 af[9];
#pragma unroll
        for (int j = 0; j < 9; ++j)
            af[j] = *(const bf16x8*)(w1ra + n15 * 288 + j * 32 + quad * 8);
#pragma unroll
        for (int g = 0; g < 4; ++g) {
            int yrow = wv * 4 + g;
            f32x4 acc = {0.0f, 0.0f, 0.0f, 0.0f};
#pragma unroll
            for (int jy = 0; jy < 3; ++jy)
#pragma unroll
                for (int jx = 0; jx < 3; ++jx) {
                    const bf16x8* bp = (const bf16x8*)(tile +
                        ((yrow + jy) * HALO + n15 + jx) * 32 + quad * 8);
                    acc = __builtin_amdgcn_mfma_f32_16x16x32_bf16(
                        af[jy * 3 + jx], *bp, acc, 0, 0, 0);
                }
            int pxl = yrow * 16 + n15;
            hidw[pxl * 9 + quad * 2]     = (unsigned)f2b(acc[0]) | ((unsigned)f2b(acc[1]) << 16);
            hidw[pxl * 9 + quad * 2 + 1] = (unsigned)f2b(acc[2]) | ((unsigned)f2b(acc[3]) << 16);
        }
#pragma unroll
        for (int j = 0; j < 8; ++j) {
            unsigned u = hidw[tid * 9 + j];
            hid1[2 * j]     = silu_f(__uint_as_float(u << 16));
            hid1[2 * j + 1] = silu_f(__uint_as_float(u & 0xffff0000u));
        }
    }
    // ---- head 2 conv (same hidw region; intra-wave DS ordering is safe) ----
    {
        bf16x8 af[9];
#pragma unroll
        for (int j = 0; j < 9; ++j)
            af[j] = *(const bf16x8*)(w1rb + n15 * 288 + j * 32 + quad * 8);
#pragma unroll
        for (int g = 0; g < 4; ++g) {
            int yrow = wv * 4 + g;
            f32x4 acc = {0.0f, 0.0f, 0.0f, 0.0f};
#pragma unroll
            for (int jy = 0; jy < 3; ++jy)
#pragma unroll
                for (int jx = 0; jx < 3; ++jx) {
                    const bf16x8* bp = (const bf16x8*)(tile +
                        ((yrow + jy) * HALO + n15 + jx) * 32 + quad * 8);
                    acc = __builtin_amdgcn_mfma_f32_16x16x32_bf16(
                        af[jy * 3 + jx], *bp, acc, 0, 0, 0);
                }
            int pxl = yrow * 16 + n15;
            hidw[pxl * 9 + quad * 2]     = (unsigned)f2b(acc[0]) | ((unsigned)f2b(acc[1]) << 16);
            hidw[pxl * 9 + quad * 2 + 1] = (unsigned)f2b(acc[2]) | ((unsigned)f2b(acc[3]) << 16);
        }
#pragma unroll
        for (int j = 0; j < 8; ++j) {
            unsigned u = hidw[tid * 9 + j];
            hid2[2 * j]     = silu_f(__uint_as_float(u << 16));
            hid2[2 * j + 1] = silu_f(__uint_as_float(u & 0xffff0000u));
        }
    }

    // ---- fused dual tail ----
    float o12a[CO], o12b[CO];
#pragma unroll
    for (int j = 0; j < CO; ++j) {
        float a = b2a[j], c = b2b[j];
#pragma unroll
        for (int i = 0; i < CH; ++i) {
            a += w2a[j * CH + i] * hid1[i];
            c += w2b[j * CH + i] * hid2[i];
        }
        o12a[j] = a; o12b[j] = c;
    }
    int px = ox + tx, py = oy + ty;
    int off1[16], off2[16]; float wg1[16], wg2[16];
    calc_off<H1, W1>(o12a, px, py, off1, wg1);
    calc_off<H2, W2>(o12b, px, py, off2, wg2);

    const float* zb1 = z1 + (size_t)b * HW1 * C;
    const float* zb2 = z2 + (size_t)b * HW2 * C;
    int p = py * W + px;
    float* d1 = y1 + (size_t)b * C * HW + p;
    float* d2 = y2 + (size_t)b * C * HW + p;
#pragma unroll
    for (int c4 = 0; c4 < 8; ++c4) {
        f32x4 a1 = {0.0f, 0.0f, 0.0f, 0.0f};
        f32x4 a2 = {0.0f, 0.0f, 0.0f, 0.0f};
#pragma unroll
        for (int j = 0; j < 16; ++j) {
            a1 += wg1[j] * *(const f32x4*)(zb1 + off1[j] + c4 * 4);
            a2 += wg2[j] * *(const f32x4*)(zb2 + off2[j] + c4 * 4);
        }
        // plane-major dense stores (256 B per wave-instruction per channel)
#pragma unroll
        for (int cc = 0; cc < 4; ++cc) {
            d1[(size_t)(c4 * 4 + cc) * HW] = a1[cc];
            d2[(size_t)(c4 * 4 + cc) * HW] = a2[cc];
        }
    }
}

// ---- per-plane means (384 blocks, float4, plane layout) -------------------
__global__ void mean3_kernel(const float* __restrict__ z0, const float* __restrict__ y1,
                             const float* __restrict__ y2, float* __restrict__ dall) {
    int id = blockIdx.x;
    int srcI = id >> 7, plane = id & 127;
    const float* base = (srcI == 0) ? z0 : (srcI == 1 ? y1 : y2);
    const float4* src = (const float4*)(base + (size_t)plane * HW);
    float s = 0.0f;
    for (int i = threadIdx.x; i < HW / 4; i += blockDim.x) {
        float4 f = src[i];
        s += f.x + f.y + f.z + f.w;
    }
#pragma unroll
    for (int o = 32; o > 0; o >>= 1) s += __shfl_down(s, o, 64);
    __shared__ float ls[4];
    if ((threadIdx.x & 63) == 0) ls[threadIdx.x >> 6] = s;
    __syncthreads();
    if (threadIdx.x == 0) {
        float t = ls[0] + ls[1] + ls[2] + ls[3];
        int b = plane >> 5, c = plane & 31;
        dall[b * 96 + srcI * 32 + c] = t * (1.0f / HW);
    }
}

// ---- gating MLP + softmax -> alpha[B*3] -----------------------------------
__global__ void gate_kernel(const float* __restrict__ dall,
                            const float* __restrict__ w1, const float* __restrict__ b1,
                            const float* __restrict__ w2, const float* __restrict__ b2,
                            float* __restrict__ alpha) {
    __shared__ float hid[B][32];
    int tid = threadIdx.x;
    int b = tid >> 5, j = tid & 31;
    float a = b1[j];
    for (int k = 0; k < 96; ++k) a += dall[b * 96 + k] * w1[k * 32 + j];
    hid[b][j] = silu_f(a);
    __syncthreads();
    if (j == 0) {
        float lg[3];
#pragma unroll
        for (int t = 0; t < 3; ++t) {
            float acc = b2[t];
            for (int jj = 0; jj < 32; ++jj) acc += hid[b][jj] * w2[jj * 3 + t];
            lg[t] = acc;
        }
        float mx = fmaxf(lg[0], fmaxf(lg[1], lg[2]));
        float e0 = __expf(lg[0] - mx), e1 = __expf(lg[1] - mx), e2 = __expf(lg[2] - mx);
        float inv = fast_rcp(e0 + e1 + e2);
        alpha[b * 3 + 0] = e0 * inv;
        alpha[b * 3 + 1] = e1 * inv;
        alpha[b * 3 + 2] = e2 * inv;
    }
}

// ---- fused mix + final 1x1 conv + residual (2 pixels/thread, packed) ------
__global__ __launch_bounds__(256, 4) void final_kernel(
        const float* __restrict__ x,
        const float* __restrict__ z0, const float* __restrict__ y1,
        const float* __restrict__ y2, const float* __restrict__ alpha,
        const float* __restrict__ fw, float* __restrict__ out) {
    __shared__ float ws[C * C];
    for (int i = threadIdx.x; i < C * C; i += blockDim.x) ws[i] = fw[i];
    __syncthreads();
    int idx = blockIdx.x * blockDim.x + threadIdx.x;
    constexpr int HP = HW / 2;
    if (idx >= B * HP) return;
    int b = idx / HP, p = (idx - b * HP) * 2;
    float a0 = alpha[b * 3], a1 = alpha[b * 3 + 1], a2 = alpha[b * 3 + 2];
    size_t base = (size_t)b * C * HW + p;
    v2f mix[C];
#pragma unroll
    for (int i = 0; i < C; ++i) {
        size_t e = base + (size_t)i * HW;
        v2f za = *(const v2f*)(z0 + e);
        v2f ya = *(const v2f*)(y1 + e);
        v2f yb = *(const v2f*)(y2 + e);
        mix[i] = a0 * za + a1 * ya + a2 * yb;
    }
#pragma unroll 4
    for (int o = 0; o < C; ++o) {
        v2f acc = {0.0f, 0.0f};
#pragma unroll
        for (int i = 0; i < C; ++i) acc += ws[o * C + i] * mix[i];
        size_t e = base + (size_t)o * HW;
        v2f xr = *(const v2f*)(x + e);
        *(v2f*)(out + e) = acc + xr;
    }
}

// ---------------------------------------------------------------------------
extern "C" void kernel_launch(void* const* d_in, const int* in_sizes, int n_in,
                              void* d_out, int out_size, void* d_ws, size_t ws_size,
                              hipStream_t stream) {
    const float* x       = (const float*)d_in[0];
    const float* ds_dw[3] = {(const float*)d_in[1],  (const float*)d_in[7],  (const float*)d_in[13]};
    const float* ds_pw[3] = {(const float*)d_in[2],  (const float*)d_in[8],  (const float*)d_in[14]};
    const float* ds_g[3]  = {(const float*)d_in[3],  (const float*)d_in[9],  (const float*)d_in[15]};
    const float* ds_b[3]  = {(const float*)d_in[4],  (const float*)d_in[10], (const float*)d_in[16]};
    const float* ds_m[3]  = {(const float*)d_in[5],  (const float*)d_in[11], (const float*)d_in[17]};
    const float* ds_v[3]  = {(const float*)d_in[6],  (const float*)d_in[12], (const float*)d_in[18]};
    const float* qproj_w = (const float*)d_in[19];
    const float* h1_w1   = (const float*)d_in[20];
    const float* h1_w2   = (const float*)d_in[21];
    const float* h1_b2   = (const float*)d_in[22];
    const float* h2_w1   = (const float*)d_in[23];
    const float* h2_w2   = (const float*)d_in[24];
    const float* h2_b2   = (const float*)d_in[25];
    const float* r_w1    = (const float*)d_in[26];
    const float* r_b1    = (const float*)d_in[27];
    const float* r_w2    = (const float*)d_in[28];
    const float* r_b2    = (const float*)d_in[29];
    const float* final_w = (const float*)d_in[30];
    float* out = (float*)d_out;

    constexpr size_t N0 = (size_t)B * C * HW;
    constexpr size_t N1 = (size_t)B * C * HW1;
    constexpr size_t N2 = (size_t)B * C * HW2;
    constexpr size_t NQ = ((size_t)B * WP * WP * 32 + 1) / 2;   // qpad (u16) in floats

    float* w = (float*)d_ws;
    float* z0   = w; w += N0;      // plane
    float* y1   = w; w += N0;      // plane
    float* y2   = w; w += N0;      // plane
    float* z1cl = w; w += N1;      // channel-last (gather source)
    float* z2cl = w; w += N2;      // channel-last (gather source)
    float* s1   = w; w += N1;
    float* s2   = w; w += N2;
    ushort_t* qpad = (ushort_t*)w; w += NQ;
    ushort_t* w1ra = (ushort_t*)w; w += 2304;   // 4608 bf16
    ushort_t* w1rb = (ushort_t*)w; w += 2304;
    float* dall  = w; w += 512;
    float* alpha = w; w += 16;
    (void)ws_size; (void)in_sizes; (void)n_in; (void)out_size;

    const int T = 256;
    auto g = [](size_t n, int t) { return (int)((n + t - 1) / t); };

    pre_kernel<<<g(N1 + 4112 + 9216, T), T, 0, stream>>>(
        x, s1, qpad, h1_w1, h2_w1, w1ra, w1rb);
    pool4_kernel<<<g(N2, T), T, 0, stream>>>(s1, s2);

    fused_ds_kernel<false, true><<<dim3((H / TILE) * (W / TILE), B), T, 0, stream>>>(
        x, ds_dw[0], ds_pw[0], ds_g[0], ds_b[0], ds_m[0], ds_v[0], qproj_w,
        z0, qpad, H, W, W / TILE);
    fused_ds_kernel<true, false><<<dim3((H1 / TILE) * (W1 / TILE), B), T, 0, stream>>>(
        s1, ds_dw[1], ds_pw[1], ds_g[1], ds_b[1], ds_m[1], ds_v[1], nullptr,
        z1cl, nullptr, H1, W1, W1 / TILE);
    fused_ds_kernel<true, false><<<dim3((H2 / TILE) * (W2 / TILE), B), T, 0, stream>>>(
        s2, ds_dw[2], ds_pw[2], ds_g[2], ds_b[2], ds_m[2], ds_v[2], nullptr,
        z2cl, nullptr, H2, W2, W2 / TILE);

    head_deform2_kernel<<<dim3((H / TILE) * (W / TILE), B), T, 0, stream>>>(
        qpad, z1cl, z2cl, w1ra, w1rb, h1_w2, h1_b2, h2_w2, h2_b2, y1, y2);

    mean3_kernel<<<384, T, 0, stream>>>(z0, y1, y2, dall);
    gate_kernel<<<1, 128, 0, stream>>>(dall, r_w1, r_b1, r_w2, r_b2, alpha);

    final_kernel<<<g((size_t)B * HW / 2, T), T, 0, stream>>>(x, z0, y1, y2, alpha, final_w, out);
}

// Round 8
// 363.577 us; speedup vs baseline: 1.4966x; 1.1347x over previous
//
#include <hip/hip_runtime.h>
#include <math.h>

// ---------------------------------------------------------------------------
// CSDM pipeline on MI355X. fp32 in/out, fp32/bf16 intermediates in d_ws.
// B=4, C=32, H=W=256. MFMA head conv; bf16 channel-last gather sources
// (16B load = 8 channels); batched gather loads (16 in flight); channel
// means fused into producer kernels (no mean pass).
// Layout law (r6): bulk WRITES plane-major dense; gather READS channel-last.
// ---------------------------------------------------------------------------

constexpr int B = 4, C = 32, H = 256, W = 256;
constexpr int HW = H * W;
constexpr int H1 = 128, W1 = 128, HW1 = H1 * W1;
constexpr int H2 = 64,  W2 = 64,  HW2 = H2 * W2;
constexpr int CH = 16;   // head hidden channels
constexpr int CO = 12;   // head output channels
constexpr int TILE = 16;
constexpr int HALO = 18;
constexpr int TAREA = HALO * HALO;   // 324
constexpr int WP = 258;              // padded q edge

typedef unsigned short ushort_t;
typedef __attribute__((ext_vector_type(8))) short bf16x8;
typedef __attribute__((ext_vector_type(4))) float f32x4;
typedef __attribute__((ext_vector_type(2))) float v2f;

static __device__ __forceinline__ float fast_rcp(float x) { return __builtin_amdgcn_rcpf(x); }
static __device__ __forceinline__ float silu_f(float x) { return x * fast_rcp(1.0f + __expf(-x)); }
static __device__ __forceinline__ v2f silu2(v2f x) {
    v2f r; r.x = silu_f(x.x); r.y = silu_f(x.y); return r;
}
static __device__ __forceinline__ float tanh_f(float x) {
    float xc = fminf(fmaxf(x, -15.0f), 15.0f);
    float e = __expf(2.0f * xc);
    return (e - 1.0f) * fast_rcp(e + 1.0f);
}
static __device__ __forceinline__ ushort_t f2b(float f) {   // fp32 -> bf16 RNE
    unsigned u = __float_as_uint(f);
    return (ushort_t)((u + 0x7fffu + ((u >> 16) & 1u)) >> 16);
}
static __device__ __forceinline__ float bl(unsigned u) { return __uint_as_float(u << 16); }
static __device__ __forceinline__ float bh(unsigned u) { return __uint_as_float(u & 0xffff0000u); }
static __device__ __forceinline__ float wave_sum(float s) {
    s += __shfl_xor(s, 32, 64); s += __shfl_xor(s, 16, 64);
    s += __shfl_xor(s, 8, 64);  s += __shfl_xor(s, 4, 64);
    s += __shfl_xor(s, 2, 64);  s += __shfl_xor(s, 1, 64);
    return s;
}

// ---- pre: pool2 + qpad border + dall zero + w1 bf16 reorder ---------------
__global__ void pre_kernel(const float* __restrict__ x, float* __restrict__ s1,
                           ushort_t* __restrict__ qpad, float* __restrict__ dall,
                           const float* __restrict__ h1w1, const float* __restrict__ h2w1,
                           ushort_t* __restrict__ w1ra, ushort_t* __restrict__ w1rb) {
    int idx = blockIdx.x * blockDim.x + threadIdx.x;
    constexpr int NP = B * C * HW1;
    if (idx < NP) {
        int wo = idx % W1; int t = idx / W1;
        int ho = t % H1;   t /= H1;
        const float* src = x + ((size_t)t * H + (size_t)ho * 2) * W + (size_t)wo * 2;
        s1[idx] = (src[0] + src[1] + src[W] + src[W + 1]) * 0.25f;
        return;
    }
    int i = idx - NP;
    if (i < 4112) {                       // qpad border (4*1028)
        int b = i / 1028, r = i % 1028;
        int y, xx;
        if (r < 258)      { y = 0;           xx = r; }
        else if (r < 516) { y = 257;         xx = r - 258; }
        else if (r < 772) { y = r - 516 + 1; xx = 0; }
        else              { y = r - 772 + 1; xx = 257; }
        uint4 z4 = {0, 0, 0, 0};
        uint4* p = (uint4*)(qpad + (((size_t)b * WP + y) * WP + xx) * 32);
        p[0] = z4; p[1] = z4; p[2] = z4; p[3] = z4;
        return;
    }
    i -= 4112;
    if (i < 512) { dall[i] = 0.0f; return; }
    i -= 512;
    if (i < 4608) {                       // w1ra[o*288 + tap*32 + ci]
        int o = i / 288, k = i - o * 288;
        int j = k >> 5, ci = k & 31;
        w1ra[i] = f2b(h1w1[(o * C + ci) * 9 + j]);
        return;
    }
    i -= 4608;
    if (i < 4608) {
        int o = i / 288, k = i - o * 288;
        int j = k >> 5, ci = k & 31;
        w1rb[i] = f2b(h2w1[(o * C + ci) * 9 + j]);
    }
}

// ---- pool by 2 (s1 -> s2) -------------------------------------------------
__global__ void pool4_kernel(const float* __restrict__ s1, float* __restrict__ s2) {
    int idx = blockIdx.x * blockDim.x + threadIdx.x;
    if (idx >= B * C * HW2) return;
    int wo = idx % W2; int t = idx / W2;
    int ho = t % H2;   t /= H2;
    const float* src = s1 + ((size_t)t * H1 + (size_t)ho * 2) * W1 + (size_t)wo * 2;
    s2[idx] = (src[0] + src[1] + src[W1] + src[W1 + 1]) * 0.25f;
}

// ---- fused ds_block: dwconv3 + 1x1 + BN + SiLU, packed f32 ----------------
// CHLAST: bf16 channel-last [b][p][c] (gather source). Else fp32 plane,
// plus q-proj (bf16 padded channel-last) and z0 channel-mean atomics.
template<bool CHLAST>
__global__ __launch_bounds__(256, 4) void fused_ds_kernel(
        const float* __restrict__ in, const float* __restrict__ dw,
        const float* __restrict__ pw, const float* __restrict__ g,
        const float* __restrict__ bb, const float* __restrict__ m,
        const float* __restrict__ v, const float* __restrict__ qw,
        float* __restrict__ out, ushort_t* __restrict__ outcl,
        ushort_t* __restrict__ qout, float* __restrict__ dall,
        int Hs, int Ws, int tilesX) {
    __shared__ unsigned tileu[16 * TAREA];     // 2-ch interleaved bf16, 20736 B
    __shared__ v2f dwp[16 * 9];
    __shared__ v2f pwp[C * 16];                // pwp[ci*16+o2] = {w[2o2][ci], w[2o2+1][ci]}
    __shared__ v2f qwp[CHLAST ? 1 : C * 16];
    __shared__ v2f scale2[16], shift2[16];
    __shared__ float zsum[CHLAST ? 1 : 4][CHLAST ? 1 : 32];
    int tid = threadIdx.x;
    int b = blockIdx.y;
    int HWs = Hs * Ws;
    int ox = (blockIdx.x % tilesX) * TILE;
    int oy = (blockIdx.x / tilesX) * TILE;

    for (int i = tid; i < 16 * 9; i += 256) {
        int c2 = i / 9, j = i - c2 * 9;
        dwp[i] = (v2f){dw[(2 * c2) * 9 + j], dw[(2 * c2 + 1) * 9 + j]};
    }
    for (int i = tid; i < C * 16; i += 256) {
        int ci = i >> 4, o2 = i & 15;
        pwp[i] = (v2f){pw[(2 * o2) * C + ci], pw[(2 * o2 + 1) * C + ci]};
        if (!CHLAST) qwp[i] = (v2f){qw[(2 * o2) * C + ci], qw[(2 * o2 + 1) * C + ci]};
    }
    if (tid < 16) {
        float s0 = g[2 * tid] * rsqrtf(v[2 * tid] + 1e-5f);
        float s1v = g[2 * tid + 1] * rsqrtf(v[2 * tid + 1] + 1e-5f);
        scale2[tid] = (v2f){s0, s1v};
        shift2[tid] = (v2f){bb[2 * tid] - m[2 * tid] * s0, bb[2 * tid + 1] - m[2 * tid + 1] * s1v};
    }
    const float* src = in + (size_t)b * C * HWs;
    for (int i = tid; i < 16 * TAREA; i += 256) {
        int c2 = i / TAREA, r = i - c2 * TAREA;
        int yy = r / HALO, xx = r - yy * HALO;
        int gy = oy - 1 + yy, gx = ox - 1 + xx;
        float v0 = 0.0f, v1 = 0.0f;
        if (gy >= 0 && gy < Hs && gx >= 0 && gx < Ws) {
            const float* sp = src + (size_t)(2 * c2) * HWs + gy * Ws + gx;
            v0 = sp[0]; v1 = sp[HWs];
        }
        tileu[i] = (unsigned)f2b(v0) | ((unsigned)f2b(v1) << 16);
    }
    __syncthreads();

    int tx = tid & 15, ty = tid >> 4;
    int off[9];
#pragma unroll
    for (int jy = 0; jy < 3; ++jy)
#pragma unroll
        for (int jx = 0; jx < 3; ++jx)
            off[jy * 3 + jx] = (ty + jy) * HALO + tx + jx;

    v2f t2[16];
#pragma unroll
    for (int c2 = 0; c2 < 16; ++c2) {
        v2f s = {0.0f, 0.0f};
        const unsigned* tp = tileu + c2 * TAREA;
#pragma unroll
        for (int j = 0; j < 9; ++j) {
            unsigned u = tp[off[j]];
            v2f val = {bl(u), bh(u)};
            s += dwp[c2 * 9 + j] * val;
        }
        t2[c2] = s;
    }

    v2f acc2[16];
#pragma unroll
    for (int o2 = 0; o2 < 16; ++o2) acc2[o2] = (v2f){0.0f, 0.0f};
#pragma unroll
    for (int i2 = 0; i2 < 16; ++i2) {
        float ta = t2[i2].x, tb = t2[i2].y;
        const v2f* r0 = pwp + (2 * i2) * 16;
        const v2f* r1 = r0 + 16;
#pragma unroll
        for (int o2 = 0; o2 < 16; ++o2)
            acc2[o2] += r0[o2] * ta + r1[o2] * tb;
    }
#pragma unroll
    for (int o2 = 0; o2 < 16; ++o2)
        acc2[o2] = silu2(acc2[o2] * scale2[o2] + shift2[o2]);

    int px = ox + tx, py = oy + ty;
    int p = py * Ws + px;
    if (CHLAST) {
        // bf16 channel-last: 32 ch -> 16 uints -> 4 uint4 stores (64 B/px)
        unsigned up[16];
#pragma unroll
        for (int j = 0; j < 16; ++j)
            up[j] = (unsigned)f2b(acc2[j].x) | ((unsigned)f2b(acc2[j].y) << 16);
        uint4* dst = (uint4*)(outcl + ((size_t)b * HWs + p) * C);
#pragma unroll
        for (int j = 0; j < 4; ++j)
            dst[j] = make_uint4(up[4 * j], up[4 * j + 1], up[4 * j + 2], up[4 * j + 3]);
    } else {
        float* dst = out + (size_t)b * C * HWs + p;
#pragma unroll
        for (int o2 = 0; o2 < 16; ++o2) {
            dst[(size_t)(2 * o2) * HWs] = acc2[o2].x;
            dst[(size_t)(2 * o2 + 1) * HWs] = acc2[o2].y;
        }
        // q projection -> bf16 padded channel-last
        v2f q2[16];
#pragma unroll
        for (int o2 = 0; o2 < 16; ++o2) q2[o2] = (v2f){0.0f, 0.0f};
#pragma unroll
        for (int i2 = 0; i2 < 16; ++i2) {
            float ta = acc2[i2].x, tb = acc2[i2].y;
            const v2f* r0 = qwp + (2 * i2) * 16;
            const v2f* r1 = r0 + 16;
#pragma unroll
            for (int o2 = 0; o2 < 16; ++o2)
                q2[o2] += r0[o2] * ta + r1[o2] * tb;
        }
        unsigned up[16];
#pragma unroll
        for (int j = 0; j < 16; ++j)
            up[j] = (unsigned)f2b(q2[j].x) | ((unsigned)f2b(q2[j].y) << 16);
        uint4* qd = (uint4*)(qout + (((size_t)b * WP + py + 1) * WP + px + 1) * 32);
#pragma unroll
        for (int j = 0; j < 4; ++j)
            qd[j] = make_uint4(up[4 * j], up[4 * j + 1], up[4 * j + 2], up[4 * j + 3]);
        // z0 channel means (wave shuffle reduce + atomics)
        int lane = tid & 63, wv = tid >> 6;
#pragma unroll
        for (int o2 = 0; o2 < 16; ++o2) {
            float sx = wave_sum(acc2[o2].x);
            float sy = wave_sum(acc2[o2].y);
            if (lane == 0) { zsum[wv][2 * o2] = sx; zsum[wv][2 * o2 + 1] = sy; }
        }
        __syncthreads();
        if (tid < 32)
            atomicAdd(&dall[b * 96 + tid],
                      (zsum[0][tid] + zsum[1][tid] + zsum[2][tid] + zsum[3][tid]) * (1.0f / HW));
    }
}

// ---- offsets/weights for one head (halfword offsets into bf16 z) ----------
template<int HC, int WC>
static __device__ __forceinline__ void calc_off(const float* o12, int px, int py,
                                                int* zoff, float* wgt) {
    float mx = fmaxf(fmaxf(o12[8], o12[9]), fmaxf(o12[10], o12[11]));
    float e0 = __expf(o12[8] - mx), e1 = __expf(o12[9] - mx);
    float e2 = __expf(o12[10] - mx), e3 = __expf(o12[11] - mx);
    float inv = fast_rcp(e0 + e1 + e2 + e3);
    float wk4[4] = {e0 * inv, e1 * inv, e2 * inv, e3 * inv};
    float xc = (px + 0.5f) * ((float)WC / (float)W) - 0.5f;
    float yc = (py + 0.5f) * ((float)HC / (float)H) - 0.5f;
#pragma unroll
    for (int k = 0; k < 4; ++k) {
        float ix = fminf(fmaxf(xc + 2.0f * tanh_f(o12[2 * k]),     0.0f), (float)(WC - 1));
        float iy = fminf(fmaxf(yc + 2.0f * tanh_f(o12[2 * k + 1]), 0.0f), (float)(HC - 1));
        float x0f = floorf(ix), y0f = floorf(iy);
        int x0 = (int)x0f, y0 = (int)y0f;
        int x1 = min(x0 + 1, WC - 1), y1 = min(y0 + 1, HC - 1);
        float wx = ix - x0f, wy = iy - y0f;
        float wk = wk4[k];
        zoff[4 * k + 0] = (y0 * WC + x0) * C; wgt[4 * k + 0] = (1.0f - wx) * (1.0f - wy) * wk;
        zoff[4 * k + 1] = (y0 * WC + x1) * C; wgt[4 * k + 1] = wx * (1.0f - wy) * wk;
        zoff[4 * k + 2] = (y1 * WC + x0) * C; wgt[4 * k + 2] = (1.0f - wx) * wy * wk;
        zoff[4 * k + 3] = (y1 * WC + x1) * C; wgt[4 * k + 3] = wx * wy * wk;
    }
}

// ---- both heads: MFMA 3x3 conv + batched bf16 gather tail + y means -------
__global__ __launch_bounds__(256, 3) void head_deform2_kernel(
        const ushort_t* __restrict__ qpad,
        const ushort_t* __restrict__ z1, const ushort_t* __restrict__ z2,
        const ushort_t* __restrict__ w1ra, const ushort_t* __restrict__ w1rb,
        const float* __restrict__ w2a, const float* __restrict__ b2a,
        const float* __restrict__ w2b, const float* __restrict__ b2b,
        float* __restrict__ y1, float* __restrict__ y2, float* __restrict__ dall) {
    __shared__ __align__(16) ushort_t tile[TAREA * C];   // 20736 B
    __shared__ __align__(8)  unsigned hidw[256 * 9];     // 9216 B, stride 9 dwords
    __shared__ float ysum[4][64];                        // 1024 B
    int tid = threadIdx.x, b = blockIdx.y;
    int ox = (blockIdx.x & 15) * TILE, oy = (blockIdx.x >> 4) * TILE;
    int lane = tid & 63, wv = tid >> 6;
    int n15 = lane & 15, quad = lane >> 4;
    int tx = tid & 15, ty = tid >> 4;

    // stage q tile (rows contiguous in padded channel-last q)
    {
        const ushort_t* base = qpad + ((size_t)b * WP + oy) * WP * 32;
        uint4* tl = (uint4*)tile;
        for (int i = tid; i < 1296; i += 256) {      // 18 rows * 72 16B-chunks
            int yy = i / 72, r = i - yy * 72;
            tl[i] = *(const uint4*)(base + ((size_t)yy * WP + ox) * 32 + r * 8);
        }
    }
    __syncthreads();

    float hid1[CH], hid2[CH];
#pragma unroll
    for (int hsel = 0; hsel < 2; ++hsel) {
        const ushort_t* w1r = hsel ? w1rb : w1ra;
        float* hid = hsel ? hid2 : hid1;
        bf16x8 af[9];
#pragma unroll
        for (int j = 0; j < 9; ++j)
            af[j] = *(const bf16x8*)(w1r + n15 * 288 + j * 32 + quad * 8);
#pragma unroll
        for (int g = 0; g < 4; ++g) {
            int yrow = wv * 4 + g;
            f32x4 acc = {0.0f, 0.0f, 0.0f, 0.0f};
#pragma unroll
            for (int jy = 0; jy < 3; ++jy)
#pragma unroll
                for (int jx = 0; jx < 3; ++jx) {
                    const bf16x8* bp = (const bf16x8*)(tile +
                        ((yrow + jy) * HALO + n15 + jx) * 32 + quad * 8);
                    acc = __builtin_amdgcn_mfma_f32_16x16x32_bf16(
                        af[jy * 3 + jx], *bp, acc, 0, 0, 0);
                }
            int pxl = yrow * 16 + n15;
            hidw[pxl * 9 + quad * 2]     = (unsigned)f2b(acc[0]) | ((unsigned)f2b(acc[1]) << 16);
            hidw[pxl * 9 + quad * 2 + 1] = (unsigned)f2b(acc[2]) | ((unsigned)f2b(acc[3]) << 16);
        }
#pragma unroll
        for (int j = 0; j < 8; ++j) {
            unsigned u = hidw[tid * 9 + j];
            hid[2 * j]     = silu_f(bl(u));
            hid[2 * j + 1] = silu_f(bh(u));
        }
    }

    // ---- fused dual tail ----
    float o12a[CO], o12b[CO];
#pragma unroll
    for (int j = 0; j < CO; ++j) {
        float a = b2a[j], c = b2b[j];
#pragma unroll
        for (int i = 0; i < CH; ++i) {
            a += w2a[j * CH + i] * hid1[i];
            c += w2b[j * CH + i] * hid2[i];
        }
        o12a[j] = a; o12b[j] = c;
    }
    int px = ox + tx, py = oy + ty;
    int off1[16], off2[16]; float wg1[16], wg2[16];
    calc_off<H1, W1>(o12a, px, py, off1, wg1);
    calc_off<H2, W2>(o12b, px, py, off2, wg2);

    const ushort_t* zb1 = z1 + (size_t)b * HW1 * C;
    const ushort_t* zb2 = z2 + (size_t)b * HW2 * C;
    int p = py * W + px;
    float* d1 = y1 + (size_t)b * C * HW + p;
    float* d2 = y2 + (size_t)b * C * HW + p;

#pragma unroll
    for (int c8 = 0; c8 < 4; ++c8) {
#pragma unroll
        for (int hsel = 0; hsel < 2; ++hsel) {
            const ushort_t* zb = hsel ? zb2 : zb1;
            const int* off = hsel ? off2 : off1;
            const float* wg = hsel ? wg2 : wg1;
            float* d = hsel ? d2 : d1;
            uint4 vv[16];
#pragma unroll
            for (int j = 0; j < 16; ++j)
                vv[j] = *(const uint4*)(zb + off[j] + c8 * 8);
            f32x4 lo = {0.0f, 0.0f, 0.0f, 0.0f};
            f32x4 hi = {0.0f, 0.0f, 0.0f, 0.0f};
#pragma unroll
            for (int j = 0; j < 16; ++j) {
                float wj = wg[j];
                lo[0] += wj * bl(vv[j].x); lo[1] += wj * bh(vv[j].x);
                lo[2] += wj * bl(vv[j].y); lo[3] += wj * bh(vv[j].y);
                hi[0] += wj * bl(vv[j].z); hi[1] += wj * bh(vv[j].z);
                hi[2] += wj * bl(vv[j].w); hi[3] += wj * bh(vv[j].w);
            }
#pragma unroll
            for (int k = 0; k < 4; ++k) {
                d[(size_t)(c8 * 8 + k) * HW]     = lo[k];
                d[(size_t)(c8 * 8 + 4 + k) * HW] = hi[k];
            }
            // channel means (wave reduce; ysum col = head*32 + channel)
#pragma unroll
            for (int k = 0; k < 8; ++k) {
                float s = wave_sum(k < 4 ? lo[k] : hi[k - 4]);
                if (lane == 0) ysum[wv][hsel * 32 + c8 * 8 + k] = s;
            }
        }
    }
    __syncthreads();
    if (tid < 64) {
        float s = ysum[0][tid] + ysum[1][tid] + ysum[2][tid] + ysum[3][tid];
        atomicAdd(&dall[b * 96 + 32 + tid], s * (1.0f / HW));
    }
}

// ---- gating MLP + softmax -> alpha[B*3] -----------------------------------
__global__ void gate_kernel(const float* __restrict__ dall,
                            const float* __restrict__ w1, const float* __restrict__ b1,
                            const float* __restrict__ w2, const float* __restrict__ b2,
                            float* __restrict__ alpha) {
    __shared__ float hid[B][32];
    int tid = threadIdx.x;
    int b = tid >> 5, j = tid & 31;
    float a = b1[j];
    for (int k = 0; k < 96; ++k) a += dall[b * 96 + k] * w1[k * 32 + j];
    hid[b][j] = silu_f(a);
    __syncthreads();
    if (j == 0) {
        float lg[3];
#pragma unroll
        for (int t = 0; t < 3; ++t) {
            float acc = b2[t];
            for (int jj = 0; jj < 32; ++jj) acc += hid[b][jj] * w2[jj * 3 + t];
            lg[t] = acc;
        }
        float mx = fmaxf(lg[0], fmaxf(lg[1], lg[2]));
        float e0 = __expf(lg[0] - mx), e1 = __expf(lg[1] - mx), e2 = __expf(lg[2] - mx);
        float inv = fast_rcp(e0 + e1 + e2);
        alpha[b * 3 + 0] = e0 * inv;
        alpha[b * 3 + 1] = e1 * inv;
        alpha[b * 3 + 2] = e2 * inv;
    }
}

// ---- fused mix + final 1x1 conv + residual (2 pixels/thread, packed) ------
__global__ __launch_bounds__(256, 4) void final_kernel(
        const float* __restrict__ x,
        const float* __restrict__ z0, const float* __restrict__ y1,
        const float* __restrict__ y2, const float* __restrict__ alpha,
        const float* __restrict__ fw, float* __restrict__ out) {
    __shared__ float ws[C * C];
    for (int i = threadIdx.x; i < C * C; i += blockDim.x) ws[i] = fw[i];
    __syncthreads();
    int idx = blockIdx.x * blockDim.x + threadIdx.x;
    constexpr int HP = HW / 2;
    if (idx >= B * HP) return;
    int b = idx / HP, p = (idx - b * HP) * 2;
    float a0 = alpha[b * 3], a1 = alpha[b * 3 + 1], a2 = alpha[b * 3 + 2];
    size_t base = (size_t)b * C * HW + p;
    v2f mix[C];
#pragma unroll
    for (int i = 0; i < C; ++i) {
        size_t e = base + (size_t)i * HW;
        v2f za = *(const v2f*)(z0 + e);
        v2f ya = *(const v2f*)(y1 + e);
        v2f yb = *(const v2f*)(y2 + e);
        mix[i] = a0 * za + a1 * ya + a2 * yb;
    }
#pragma unroll 4
    for (int o = 0; o < C; ++o) {
        v2f acc = {0.0f, 0.0f};
#pragma unroll
        for (int i = 0; i < C; ++i) acc += ws[o * C + i] * mix[i];
        size_t e = base + (size_t)o * HW;
        v2f xr = *(const v2f*)(x + e);
        *(v2f*)(out + e) = acc + xr;
    }
}

// ---------------------------------------------------------------------------
extern "C" void kernel_launch(void* const* d_in, const int* in_sizes, int n_in,
                              void* d_out, int out_size, void* d_ws, size_t ws_size,
                              hipStream_t stream) {
    const float* x       = (const float*)d_in[0];
    const float* ds_dw[3] = {(const float*)d_in[1],  (const float*)d_in[7],  (const float*)d_in[13]};
    const float* ds_pw[3] = {(const float*)d_in[2],  (const float*)d_in[8],  (const float*)d_in[14]};
    const float* ds_g[3]  = {(const float*)d_in[3],  (const float*)d_in[9],  (const float*)d_in[15]};
    const float* ds_b[3]  = {(const float*)d_in[4],  (const float*)d_in[10], (const float*)d_in[16]};
    const float* ds_m[3]  = {(const float*)d_in[5],  (const float*)d_in[11], (const float*)d_in[17]};
    const float* ds_v[3]  = {(const float*)d_in[6],  (const float*)d_in[12], (const float*)d_in[18]};
    const float* qproj_w = (const float*)d_in[19];
    const float* h1_w1   = (const float*)d_in[20];
    const float* h1_w2   = (const float*)d_in[21];
    const float* h1_b2   = (const float*)d_in[22];
    const float* h2_w1   = (const float*)d_in[23];
    const float* h2_w2   = (const float*)d_in[24];
    const float* h2_b2   = (const float*)d_in[25];
    const float* r_w1    = (const float*)d_in[26];
    const float* r_b1    = (const float*)d_in[27];
    const float* r_w2    = (const float*)d_in[28];
    const float* r_b2    = (const float*)d_in[29];
    const float* final_w = (const float*)d_in[30];
    float* out = (float*)d_out;

    constexpr size_t N0 = (size_t)B * C * HW;
    constexpr size_t N1 = (size_t)B * C * HW1;
    constexpr size_t N2 = (size_t)B * C * HW2;
    constexpr size_t NQ = ((size_t)B * WP * WP * 32 + 1) / 2;   // qpad (u16) in floats

    float* w = (float*)d_ws;
    float* z0   = w; w += N0;      // plane fp32
    float* y1   = w; w += N0;      // plane fp32
    float* y2   = w; w += N0;      // plane fp32
    ushort_t* z1cl = (ushort_t*)w; w += N1 / 2;   // bf16 channel-last
    ushort_t* z2cl = (ushort_t*)w; w += N2 / 2;   // bf16 channel-last
    float* s1   = w; w += N1;
    float* s2   = w; w += N2;
    ushort_t* qpad = (ushort_t*)w; w += NQ;
    ushort_t* w1ra = (ushort_t*)w; w += 2304;   // 4608 bf16
    ushort_t* w1rb = (ushort_t*)w; w += 2304;
    float* dall  = w; w += 512;
    float* alpha = w; w += 16;
    (void)ws_size; (void)in_sizes; (void)n_in; (void)out_size;

    const int T = 256;
    auto g = [](size_t n, int t) { return (int)((n + t - 1) / t); };

    pre_kernel<<<g(N1 + 4112 + 512 + 9216, T), T, 0, stream>>>(
        x, s1, qpad, dall, h1_w1, h2_w1, w1ra, w1rb);
    pool4_kernel<<<g(N2, T), T, 0, stream>>>(s1, s2);

    fused_ds_kernel<false><<<dim3((H / TILE) * (W / TILE), B), T, 0, stream>>>(
        x, ds_dw[0], ds_pw[0], ds_g[0], ds_b[0], ds_m[0], ds_v[0], qproj_w,
        z0, nullptr, qpad, dall, H, W, W / TILE);
    fused_ds_kernel<true><<<dim3((H1 / TILE) * (W1 / TILE), B), T, 0, stream>>>(
        s1, ds_dw[1], ds_pw[1], ds_g[1], ds_b[1], ds_m[1], ds_v[1], nullptr,
        nullptr, z1cl, nullptr, nullptr, H1, W1, W1 / TILE);
    fused_ds_kernel<true><<<dim3((H2 / TILE) * (W2 / TILE), B), T, 0, stream>>>(
        s2, ds_dw[2], ds_pw[2], ds_g[2], ds_b[2], ds_m[2], ds_v[2], nullptr,
        nullptr, z2cl, nullptr, nullptr, H2, W2, W2 / TILE);

    head_deform2_kernel<<<dim3((H / TILE) * (W / TILE), B), T, 0, stream>>>(
        qpad, z1cl, z2cl, w1ra, w1rb, h1_w2, h1_b2, h2_w2, h2_b2, y1, y2, dall);

    gate_kernel<<<1, 128, 0, stream>>>(dall, r_w1, r_b1, r_w2, r_b2, alpha);

    final_kernel<<<g((size_t)B * HW / 2, T), T, 0, stream>>>(x, z0, y1, y2, alpha, final_w, out);
}